// Round 2
// baseline (1595.515 us; speedup 1.0000x reference)
//
#include <hip/hip_runtime.h>
#include <hip/hip_bf16.h>
#include <cfloat>

// Problem constants (fixed by the reference setup)
#define NTOT    65536      // B*D*H*W = 4*16*32*32
#define KCODES  1024
#define DM      256
#define SPAT    16384      // D*H*W
#define ZQ_SIZE 16777216   // B*C*D*H*W = 4*256*16384

// d_out layout (floats): [0, ZQ_SIZE) z_q | [ZQ_SIZE] vq_loss | [ZQ_SIZE+1, +65536) indices
// ws layout (float offsets)
#define WS_ENORM 0          // 1024
#define WS_CNT   1024       // 1024
#define WS_CSIZE 2048       // 1024
#define WS_LOSSP 3072       // 8192 partials
#define WS_ESUM  11264      // 262144
#define WS_NEWE  273408     // 262144
#define WS_IDX   535552     // 65536 (int32)

__global__ __launch_bounds__(256) void enorm_kernel(const float* __restrict__ embed,
                                                    float* __restrict__ enorm) {
    int k = blockIdx.x;
    int t = threadIdx.x;
    float v = embed[k * DM + t];
    v *= v;
    #pragma unroll
    for (int m = 32; m > 0; m >>= 1) v += __shfl_xor(v, m);
    __shared__ float sm[4];
    if ((t & 63) == 0) sm[t >> 6] = v;
    __syncthreads();
    if (t == 0) enorm[k] = sm[0] + sm[1] + sm[2] + sm[3];
}

// 1024 blocks x 256 threads; block handles 64 rows (consecutive s, same b) x all 1024 codes.
__global__ __launch_bounds__(256, 4) void argmin_kernel(
    const float* __restrict__ z, const float* __restrict__ embed,
    const float* __restrict__ enorm, int* __restrict__ idx_out,
    float* __restrict__ dout) {
    __shared__ float zs[64][68];   // [s][c], pad 4 keeps float4 alignment, conflict-light
    __shared__ float es[64][68];   // [k][c]

    const int tid = threadIdx.x;
    const int n0  = blockIdx.x * 64;
    const int b   = n0 >> 14;
    const int s0  = n0 & 16383;
    const int ti  = tid >> 4;    // 0..15 row group   (rows ti + i*16)
    const int tj  = tid & 15;    // 0..15 code group  (codes tj + j*16)
    const int sl  = tid & 63;
    const int cg  = tid >> 6;    // 0..3
    const int kg4 = tid >> 4;    // 0..15 (es staging)
    const int cl4 = tid & 15;

    float best[4]  = {FLT_MAX, FLT_MAX, FLT_MAX, FLT_MAX};
    int   bestk[4] = {0, 0, 0, 0};

    for (int k0 = 0; k0 < KCODES; k0 += 64) {
        float acc[4][4] = {};
        for (int c0 = 0; c0 < DM; c0 += 64) {
            __syncthreads();   // protect LDS from previous tile's readers
            // stage z tile: 64 s x 64 c (global coalesced along s, transposed write)
            {
                const float* zp = z + (size_t)(b * DM + c0 + cg * 16) * SPAT + s0 + sl;
                #pragma unroll
                for (int u = 0; u < 16; ++u)
                    zs[sl][cg * 16 + u] = zp[(size_t)u * SPAT];
            }
            // stage e tile: 64 k x 64 c (row-major, float4)
            {
                #pragma unroll
                for (int v = 0; v < 4; ++v) {
                    int kk = kg4 + v * 16;
                    float4 val = *(const float4*)&embed[(size_t)(k0 + kk) * DM + c0 + cl4 * 4];
                    *(float4*)&es[kk][cl4 * 4] = val;
                }
            }
            __syncthreads();
            #pragma unroll
            for (int c = 0; c < 64; c += 4) {
                float4 za[4], eb[4];
                #pragma unroll
                for (int i = 0; i < 4; ++i) za[i] = *(const float4*)&zs[ti + i * 16][c];
                #pragma unroll
                for (int j = 0; j < 4; ++j) eb[j] = *(const float4*)&es[tj + j * 16][c];
                #pragma unroll
                for (int i = 0; i < 4; ++i)
                    #pragma unroll
                    for (int j = 0; j < 4; ++j) {
                        acc[i][j] = fmaf(za[i].x, eb[j].x, acc[i][j]);
                        acc[i][j] = fmaf(za[i].y, eb[j].y, acc[i][j]);
                        acc[i][j] = fmaf(za[i].z, eb[j].z, acc[i][j]);
                        acc[i][j] = fmaf(za[i].w, eb[j].w, acc[i][j]);
                    }
            }
        }
        // running argmin update: v = |e|^2 - 2*dot (row-constant |z|^2 dropped)
        #pragma unroll
        for (int j = 0; j < 4; ++j) {
            int q = k0 + tj + j * 16;
            float en = enorm[q];
            #pragma unroll
            for (int i = 0; i < 4; ++i) {
                float v = fmaf(-2.0f, acc[i][j], en);
                if (v < best[i]) { best[i] = v; bestk[i] = q; }  // strict <: keeps smallest q
            }
        }
    }
    // reduce over the 16 tj lanes (same wave), tie -> smaller k
    #pragma unroll
    for (int i = 0; i < 4; ++i) {
        float bd = best[i];
        int   bk = bestk[i];
        #pragma unroll
        for (int m = 1; m < 16; m <<= 1) {
            float od = __shfl_xor(bd, m);
            int   ok = __shfl_xor(bk, m);
            if (od < bd || (od == bd && ok < bk)) { bd = od; bk = ok; }
        }
        if (tj == 0) {
            int n = n0 + ti + i * 16;
            idx_out[n] = bk;
            dout[ZQ_SIZE + 1 + n] = (float)bk;
        }
    }
}

// histogram + segment-sum via atomics. 1024 blocks x 256 threads, 64 rows/block.
__global__ __launch_bounds__(256) void scatter_kernel(
    const float* __restrict__ z, const int* __restrict__ idx,
    float* __restrict__ cnt, float* __restrict__ esum) {
    int tid = threadIdx.x;
    int n0 = blockIdx.x * 64;
    int b = n0 >> 14, s0 = n0 & 16383;
    int sl = tid & 63, cg = tid >> 6;
    int n = n0 + sl;
    int k = idx[n];
    if (cg == 0) atomicAdd(&cnt[k], 1.0f);
    float* dst = esum + (size_t)k * DM + cg * 64;
    const float* zp = z + (size_t)(b * DM + cg * 64) * SPAT + s0 + sl;
    #pragma unroll 8
    for (int u = 0; u < 64; ++u)
        atomicAdd(&dst[u], zp[(size_t)u * SPAT]);
}

__global__ __launch_bounds__(1024) void ema_kernel(const float* __restrict__ ema_cs,
                                                   const float* __restrict__ cnt,
                                                   float* __restrict__ csize) {
    int k = threadIdx.x;   // 1024 threads
    float ncs = 0.99f * ema_cs[k] + 0.01f * cnt[k];
    float v = ncs;
    #pragma unroll
    for (int m = 32; m > 0; m >>= 1) v += __shfl_xor(v, m);
    __shared__ float sm[16];
    if ((k & 63) == 0) sm[k >> 6] = v;
    __syncthreads();
    __shared__ float ns;
    if (k == 0) {
        float t = 0.f;
        #pragma unroll
        for (int i = 0; i < 16; ++i) t += sm[i];
        ns = t;
    }
    __syncthreads();
    float n = ns;
    csize[k] = (ncs + 1e-5f) / (n + 0.01024f) * n;
}

__global__ __launch_bounds__(256) void newembed_kernel(
    const float* __restrict__ ema_es, const float* __restrict__ esum,
    const float* __restrict__ csize, float* __restrict__ newe) {
    int k = blockIdx.x, c = threadIdx.x;
    size_t i = (size_t)k * DM + c;
    newe[i] = (0.99f * ema_es[i] + 0.01f * esum[i]) / csize[k];
}

// z_q gather into (B,C,D,H,W) layout + per-block loss partial (deterministic 2-stage).
// 8192 blocks x 256 threads x 8 elements = 16777216.
__global__ __launch_bounds__(256) void output_kernel(
    const float* __restrict__ z, const float* __restrict__ newe,
    const int* __restrict__ idx, float* __restrict__ dout,
    float* __restrict__ lossp) {
    int gid = blockIdx.x * 256 + threadIdx.x;
    float lsum = 0.f;
    #pragma unroll
    for (int it = 0; it < 8; ++it) {
        int o = gid + it * (8192 * 256);
        int s = o & 16383, t2 = o >> 14;   // t2 in [0,1024)
        int c = t2 & 255, b = t2 >> 8;
        int n = (b << 14) + s;
        int k = idx[n];
        float v = newe[(size_t)k * DM + c];
        float zv = z[o];
        dout[o] = v;
        float d = zv - v;
        lsum = fmaf(d, d, lsum);
    }
    #pragma unroll
    for (int m = 32; m > 0; m >>= 1) lsum += __shfl_xor(lsum, m);
    __shared__ float sm[4];
    int t = threadIdx.x;
    if ((t & 63) == 0) sm[t >> 6] = lsum;
    __syncthreads();
    if (t == 0) lossp[blockIdx.x] = sm[0] + sm[1] + sm[2] + sm[3];
}

__global__ __launch_bounds__(256) void loss_final_kernel(const float* __restrict__ lossp,
                                                         float* __restrict__ dout) {
    int t = threadIdx.x;
    float v = 0.f;
    for (int i = t; i < 8192; i += 256) v += lossp[i];
    #pragma unroll
    for (int m = 32; m > 0; m >>= 1) v += __shfl_xor(v, m);
    __shared__ float sm[4];
    if ((t & 63) == 0) sm[t >> 6] = v;
    __syncthreads();
    if (t == 0) dout[ZQ_SIZE] = 0.25f * ((sm[0] + sm[1] + sm[2] + sm[3]) / 16777216.0f);
}

extern "C" void kernel_launch(void* const* d_in, const int* in_sizes, int n_in,
                              void* d_out, int out_size, void* d_ws, size_t ws_size,
                              hipStream_t stream) {
    const float* z      = (const float*)d_in[0];
    const float* embed  = (const float*)d_in[1];
    const float* ema_cs = (const float*)d_in[2];
    const float* ema_es = (const float*)d_in[3];
    float* out = (float*)d_out;
    float* ws  = (float*)d_ws;

    float* enorm = ws + WS_ENORM;
    float* cnt   = ws + WS_CNT;
    float* csize = ws + WS_CSIZE;
    float* lossp = ws + WS_LOSSP;
    float* esum  = ws + WS_ESUM;
    float* newe  = ws + WS_NEWE;
    int*   idx   = (int*)(ws + WS_IDX);

    // zero enorm..esum (cnt + esum need zeros; rest fully overwritten)
    hipMemsetAsync(d_ws, 0, (size_t)(WS_ESUM + 262144) * sizeof(float), stream);

    enorm_kernel<<<KCODES, 256, 0, stream>>>(embed, enorm);
    argmin_kernel<<<NTOT / 64, 256, 0, stream>>>(z, embed, enorm, idx, out);
    scatter_kernel<<<NTOT / 64, 256, 0, stream>>>(z, idx, cnt, esum);
    ema_kernel<<<1, 1024, 0, stream>>>(ema_cs, cnt, csize);
    newembed_kernel<<<KCODES, 256, 0, stream>>>(ema_es, esum, csize, newe);
    output_kernel<<<8192, 256, 0, stream>>>(z, newe, idx, out, lossp);
    loss_final_kernel<<<1, 256, 0, stream>>>(lossp, out);
}

// Round 3
// 775.053 us; speedup vs baseline: 2.0586x; 2.0586x over previous
//
#include <hip/hip_runtime.h>
#include <hip/hip_bf16.h>
#include <cfloat>

// Problem constants (fixed by the reference setup)
#define NTOT    65536      // B*D*H*W = 4*16*32*32
#define KCODES  1024
#define DM      256
#define SPAT    16384      // D*H*W
#define ZQ_SIZE 16777216   // B*C*D*H*W = 4*256*16384

// d_out layout (floats): [0, ZQ_SIZE) z_q | [ZQ_SIZE] vq_loss | [ZQ_SIZE+1, +65536) indices
// NOTE: d_out[0..ZQ_SIZE) doubles as scratch for the transposed z (zt) until
// output_kernel overwrites it (stream-ordered, no overlap in time).
//
// ws layout (4-byte units)
#define WS_ENORM 0          // 1024 f
#define WS_CSIZE 1024       // 1024 f
#define WS_START 2048       // 1025 i (pad to 1056)
#define WS_LOSSP 3104       // 8192 f
#define WS_HIST  11296      // 256*1024 i
#define WS_SORT  273440     // 65536 i
#define WS_IDX   338976     // 65536 i
#define WS_NEWE  404512     // 262144 f   (ends 666656 ~ 2.67 MB)

__global__ __launch_bounds__(256) void enorm_kernel(const float* __restrict__ embed,
                                                    float* __restrict__ enorm) {
    int k = blockIdx.x;
    int t = threadIdx.x;
    float v = embed[k * DM + t];
    v *= v;
    #pragma unroll
    for (int m = 32; m > 0; m >>= 1) v += __shfl_xor(v, m);
    __shared__ float sm[4];
    if ((t & 63) == 0) sm[t >> 6] = v;
    __syncthreads();
    if (t == 0) enorm[k] = sm[0] + sm[1] + sm[2] + sm[3];
}

// 1024 blocks x 256 threads; block handles 64 rows (consecutive s, same b) x all 1024 codes.
__global__ __launch_bounds__(256, 4) void argmin_kernel(
    const float* __restrict__ z, const float* __restrict__ embed,
    const float* __restrict__ enorm, int* __restrict__ idx_out,
    float* __restrict__ dout) {
    __shared__ float zs[64][68];   // [s][c]
    __shared__ float es[64][68];   // [k][c]

    const int tid = threadIdx.x;
    const int n0  = blockIdx.x * 64;
    const int b   = n0 >> 14;
    const int s0  = n0 & 16383;
    const int ti  = tid >> 4;    // 0..15 row group
    const int tj  = tid & 15;    // 0..15 code group
    const int sl  = tid & 63;
    const int cg  = tid >> 6;    // 0..3
    const int kg4 = tid >> 4;    // 0..15 (es staging)
    const int cl4 = tid & 15;

    float best[4]  = {FLT_MAX, FLT_MAX, FLT_MAX, FLT_MAX};
    int   bestk[4] = {0, 0, 0, 0};

    for (int k0 = 0; k0 < KCODES; k0 += 64) {
        float acc[4][4] = {};
        for (int c0 = 0; c0 < DM; c0 += 64) {
            __syncthreads();
            {
                const float* zp = z + (size_t)(b * DM + c0 + cg * 16) * SPAT + s0 + sl;
                #pragma unroll
                for (int u = 0; u < 16; ++u)
                    zs[sl][cg * 16 + u] = zp[(size_t)u * SPAT];
            }
            {
                #pragma unroll
                for (int v = 0; v < 4; ++v) {
                    int kk = kg4 + v * 16;
                    float4 val = *(const float4*)&embed[(size_t)(k0 + kk) * DM + c0 + cl4 * 4];
                    *(float4*)&es[kk][cl4 * 4] = val;
                }
            }
            __syncthreads();
            #pragma unroll
            for (int c = 0; c < 64; c += 4) {
                float4 za[4], eb[4];
                #pragma unroll
                for (int i = 0; i < 4; ++i) za[i] = *(const float4*)&zs[ti + i * 16][c];
                #pragma unroll
                for (int j = 0; j < 4; ++j) eb[j] = *(const float4*)&es[tj + j * 16][c];
                #pragma unroll
                for (int i = 0; i < 4; ++i)
                    #pragma unroll
                    for (int j = 0; j < 4; ++j) {
                        acc[i][j] = fmaf(za[i].x, eb[j].x, acc[i][j]);
                        acc[i][j] = fmaf(za[i].y, eb[j].y, acc[i][j]);
                        acc[i][j] = fmaf(za[i].z, eb[j].z, acc[i][j]);
                        acc[i][j] = fmaf(za[i].w, eb[j].w, acc[i][j]);
                    }
            }
        }
        #pragma unroll
        for (int j = 0; j < 4; ++j) {
            int q = k0 + tj + j * 16;
            float en = enorm[q];
            #pragma unroll
            for (int i = 0; i < 4; ++i) {
                float v = fmaf(-2.0f, acc[i][j], en);
                if (v < best[i]) { best[i] = v; bestk[i] = q; }
            }
        }
    }
    #pragma unroll
    for (int i = 0; i < 4; ++i) {
        float bd = best[i];
        int   bk = bestk[i];
        #pragma unroll
        for (int m = 1; m < 16; m <<= 1) {
            float od = __shfl_xor(bd, m);
            int   ok = __shfl_xor(bk, m);
            if (od < bd || (od == bd && ok < bk)) { bd = od; bk = ok; }
        }
        if (tj == 0) {
            int n = n0 + ti + i * 16;
            idx_out[n] = bk;
            dout[ZQ_SIZE + 1 + n] = (float)bk;
        }
    }
}

// z (b,c,s) -> zt[n][c], n = b*16384+s. 4096 blocks x 256 thr, 64s x 64c tiles.
__global__ __launch_bounds__(256) void transpose_kernel(const float* __restrict__ z,
                                                        float* __restrict__ zt) {
    __shared__ float zs[64][68];
    int bi = blockIdx.x;
    int st = bi & 255, rest = bi >> 8;
    int ct = rest & 3, b = rest >> 2;
    int n0 = b * SPAT + st * 64;
    int c0 = ct * 64;
    int tid = threadIdx.x;
    int sl = tid & 63, cg = tid >> 6;
    {
        const float* zp = z + (size_t)(b * DM + c0 + cg * 16) * SPAT + (st * 64) + sl;
        #pragma unroll
        for (int u = 0; u < 16; ++u)
            zs[sl][cg * 16 + u] = zp[(size_t)u * SPAT];
    }
    __syncthreads();
    int cc = tid & 15, rr = tid >> 4;
    #pragma unroll
    for (int u = 0; u < 4; ++u) {
        int row = rr + u * 16;
        float4 v = *(const float4*)&zs[row][cc * 4];
        *(float4*)&zt[(size_t)(n0 + row) * DM + c0 + cc * 4] = v;
    }
}

// per-256-row-chunk histogram (LDS atomics only). 256 blocks x 256 thr.
__global__ __launch_bounds__(256) void hist_kernel(const int* __restrict__ idx,
                                                   int* __restrict__ hist) {
    __shared__ int lh[KCODES];
    int ch = blockIdx.x, t = threadIdx.x;
    #pragma unroll
    for (int u = 0; u < 4; ++u) lh[t + u * 256] = 0;
    __syncthreads();
    int k = idx[ch * 256 + t];
    atomicAdd(&lh[k], 1);
    __syncthreads();
    #pragma unroll
    for (int u = 0; u < 4; ++u)
        hist[ch * KCODES + t + u * 256] = lh[t + u * 256];
}

// single block, 1024 threads: column-prefix over chunks (in place), exclusive
// scan over k -> start[], fused EMA cluster-size math -> csize[].
__global__ __launch_bounds__(1024) void scan_kernel(
    int* __restrict__ hist, const float* __restrict__ ema_cs,
    int* __restrict__ start, float* __restrict__ csize) {
    int k = threadIdx.x;
    int run = 0;
    for (int ch = 0; ch < 256; ++ch) {
        int t = hist[ch * KCODES + k];
        hist[ch * KCODES + k] = run;
        run += t;
    }
    int lane = k & 63, wv = k >> 6;
    int v = run;
    #pragma unroll
    for (int d = 1; d < 64; d <<= 1) {
        int t = __shfl_up(v, d);
        if (lane >= d) v += t;
    }
    __shared__ int wsum[16];
    if (lane == 63) wsum[wv] = v;
    __syncthreads();
    __shared__ int wpre[16];
    if (k == 0) {
        int s = 0;
        #pragma unroll
        for (int i = 0; i < 16; ++i) { wpre[i] = s; s += wsum[i]; }
    }
    __syncthreads();
    int excl = wpre[wv] + v - run;
    start[k] = excl;
    if (k == 1023) start[1024] = excl + run;
    // EMA + cluster size
    float ncs = 0.99f * ema_cs[k] + 0.01f * (float)run;
    float r = ncs;
    #pragma unroll
    for (int m = 32; m > 0; m >>= 1) r += __shfl_xor(r, m);
    __shared__ float fs[16];
    if (lane == 0) fs[wv] = r;
    __syncthreads();
    __shared__ float nt;
    if (k == 0) {
        float s = 0.f;
        #pragma unroll
        for (int i = 0; i < 16; ++i) s += fs[i];
        nt = s;
    }
    __syncthreads();
    float n = nt;
    csize[k] = (ncs + 1e-5f) / (n + 1024.0f * 1e-5f) * n;
}

// stable rank within chunk + scatter row id. 256 blocks x 256 thr.
__global__ __launch_bounds__(256) void rank_scatter_kernel(
    const int* __restrict__ idx, const int* __restrict__ hist,
    const int* __restrict__ start, int* __restrict__ sorted) {
    __shared__ int lidx[256];
    int ch = blockIdx.x, t = threadIdx.x;
    int k = idx[ch * 256 + t];
    lidx[t] = k;
    __syncthreads();
    int rank = 0;
    for (int j = 0; j < 255; ++j)
        if (j < t && lidx[j] == k) ++rank;
    sorted[start[k] + hist[ch * KCODES + k] + rank] = ch * 256 + t;
}

// one block per code: coalesced row gather-sum from zt, fused newembed.
__global__ __launch_bounds__(256) void gather_kernel(
    const float* __restrict__ zt, const int* __restrict__ sorted,
    const int* __restrict__ start, const float* __restrict__ ema_es,
    const float* __restrict__ csize, float* __restrict__ newe) {
    int k = blockIdx.x, c = threadIdx.x;
    int s0 = start[k], s1 = start[k + 1];
    float acc = 0.f;
    for (int i = s0; i < s1; ++i) {
        int n = sorted[i];
        acc += zt[(size_t)n * DM + c];
    }
    size_t o = (size_t)k * DM + c;
    newe[o] = (0.99f * ema_es[o] + 0.01f * acc) / csize[k];
}

// z_q gather into (B,C,D,H,W) layout + per-block loss partial.
// 8192 blocks x 256 threads x 8 elements = 16777216. Overwrites zt region.
__global__ __launch_bounds__(256) void output_kernel(
    const float* __restrict__ z, const float* __restrict__ newe,
    const int* __restrict__ idx, float* __restrict__ dout,
    float* __restrict__ lossp) {
    int gid = blockIdx.x * 256 + threadIdx.x;
    float lsum = 0.f;
    #pragma unroll
    for (int it = 0; it < 8; ++it) {
        int o = gid + it * (8192 * 256);
        int s = o & 16383, t2 = o >> 14;
        int c = t2 & 255, b = t2 >> 8;
        int n = (b << 14) + s;
        int k = idx[n];
        float v = newe[(size_t)k * DM + c];
        float zv = z[o];
        dout[o] = v;
        float d = zv - v;
        lsum = fmaf(d, d, lsum);
    }
    #pragma unroll
    for (int m = 32; m > 0; m >>= 1) lsum += __shfl_xor(lsum, m);
    __shared__ float sm[4];
    int t = threadIdx.x;
    if ((t & 63) == 0) sm[t >> 6] = lsum;
    __syncthreads();
    if (t == 0) lossp[blockIdx.x] = sm[0] + sm[1] + sm[2] + sm[3];
}

__global__ __launch_bounds__(256) void loss_final_kernel(const float* __restrict__ lossp,
                                                         float* __restrict__ dout) {
    int t = threadIdx.x;
    float v = 0.f;
    for (int i = t; i < 8192; i += 256) v += lossp[i];
    #pragma unroll
    for (int m = 32; m > 0; m >>= 1) v += __shfl_xor(v, m);
    __shared__ float sm[4];
    if ((t & 63) == 0) sm[t >> 6] = v;
    __syncthreads();
    if (t == 0) dout[ZQ_SIZE] = 0.25f * ((sm[0] + sm[1] + sm[2] + sm[3]) / 16777216.0f);
}

extern "C" void kernel_launch(void* const* d_in, const int* in_sizes, int n_in,
                              void* d_out, int out_size, void* d_ws, size_t ws_size,
                              hipStream_t stream) {
    const float* z      = (const float*)d_in[0];
    const float* embed  = (const float*)d_in[1];
    const float* ema_cs = (const float*)d_in[2];
    const float* ema_es = (const float*)d_in[3];
    float* out = (float*)d_out;
    float* ws  = (float*)d_ws;

    float* enorm = ws + WS_ENORM;
    float* csize = ws + WS_CSIZE;
    int*   start = (int*)(ws + WS_START);
    float* lossp = ws + WS_LOSSP;
    int*   hist  = (int*)(ws + WS_HIST);
    int*   sortd = (int*)(ws + WS_SORT);
    int*   idx   = (int*)(ws + WS_IDX);
    float* newe  = ws + WS_NEWE;
    float* zt    = out;   // d_out[0..ZQ_SIZE) as scratch until output_kernel

    enorm_kernel<<<KCODES, 256, 0, stream>>>(embed, enorm);
    argmin_kernel<<<NTOT / 64, 256, 0, stream>>>(z, embed, enorm, idx, out);
    transpose_kernel<<<4096, 256, 0, stream>>>(z, zt);
    hist_kernel<<<256, 256, 0, stream>>>(idx, hist);
    scan_kernel<<<1, 1024, 0, stream>>>(hist, ema_cs, start, csize);
    rank_scatter_kernel<<<256, 256, 0, stream>>>(idx, hist, start, sortd);
    gather_kernel<<<KCODES, 256, 0, stream>>>(zt, sortd, start, ema_es, csize, newe);
    output_kernel<<<8192, 256, 0, stream>>>(z, newe, idx, out, lossp);
    loss_final_kernel<<<1, 256, 0, stream>>>(lossp, out);
}

// Round 4
// 732.242 us; speedup vs baseline: 2.1789x; 1.0585x over previous
//
#include <hip/hip_runtime.h>
#include <hip/hip_bf16.h>
#include <cfloat>

// Problem constants (fixed by the reference setup)
#define NTOT    65536      // B*D*H*W = 4*16*32*32
#define KCODES  1024
#define DM      256
#define SPAT    16384      // D*H*W
#define ZQ_SIZE 16777216   // B*C*D*H*W = 4*256*16384

// d_out layout (floats): [0, ZQ_SIZE) z_q | [ZQ_SIZE] vq_loss | [ZQ_SIZE+1, +65536) indices
// d_out[0..ZQ_SIZE) doubles as scratch for transposed z (zt) until output_kernel.
//
// ws layout (4-byte units)
#define WS_ENORM 0          // 1024 f
#define WS_CSIZE 1024       // 1024 f
#define WS_START 2048       // 1025 i (pad to 1056)
#define WS_LOSSP 3104       // 8192 f
#define WS_HIST  11296      // 256*1024 i
#define WS_SORT  273440     // 65536 i
#define WS_IDX   338976     // 65536 i
#define WS_NEWE  404512     // 262144 f

__global__ __launch_bounds__(256) void enorm_kernel(const float* __restrict__ embed,
                                                    float* __restrict__ enorm) {
    int k = blockIdx.x;
    int t = threadIdx.x;
    float v = embed[k * DM + t];
    v *= v;
    #pragma unroll
    for (int m = 32; m > 0; m >>= 1) v += __shfl_xor(v, m);
    __shared__ float sm[4];
    if ((t & 63) == 0) sm[t >> 6] = v;
    __syncthreads();
    if (t == 0) enorm[k] = sm[0] + sm[1] + sm[2] + sm[3];
}

// 1024 blocks x 256 threads; block = 64 rows x all 1024 codes.
// k-tile 128, c-chunk 64, micro-tile 4 rows x 8 codes per thread.
// Pipelined: global loads for stage it+1 issue before inner FMA of stage it.
// Also emits the z-transpose (zt) during k0==0 stages.
__global__ __launch_bounds__(256, 3) void argmin_kernel(
    const float* __restrict__ z, const float* __restrict__ embed,
    const float* __restrict__ enorm, int* __restrict__ idx_out,
    float* __restrict__ dout, float* __restrict__ zt) {
    __shared__ float zs[64][68];    // [s][c] c-chunk of 64 (+4 pad)
    __shared__ float es[128][68];   // [k][c]

    const int tid = threadIdx.x;
    const int n0  = blockIdx.x * 64;
    const int b   = n0 >> 14;
    const int s0  = n0 & 16383;
    const int ti  = tid >> 4;      // 0..15 -> rows ti + i*16
    const int tj  = tid & 15;      // 0..15 -> codes tj + j*16 (within k-tile)
    const int sl  = tid & 63;      // z-stage row
    const int cg  = tid >> 6;      // z-stage col group (0..3)
    const int ex  = tid >> 4;      // e-stage row base
    const int ec  = (tid & 15) * 4; // e-stage col (float4)

    float best[4]  = {FLT_MAX, FLT_MAX, FLT_MAX, FLT_MAX};
    int   bestk[4] = {0, 0, 0, 0};
    float acc[4][8];

    float  zr[16];   // staged z regs
    float4 er[8];    // staged e regs

    // prologue: load stage 0 (k0=0, c0=0)
    {
        const float* zp = z + (size_t)(b * DM + cg * 16) * SPAT + s0 + sl;
        #pragma unroll
        for (int u = 0; u < 16; ++u) zr[u] = zp[(size_t)u * SPAT];
        #pragma unroll
        for (int v = 0; v < 8; ++v)
            er[v] = *(const float4*)&embed[(size_t)(ex + v * 16) * DM + ec];
    }

    for (int it = 0; it < 32; ++it) {
        const int c0 = (it & 3) * 64;
        const int k0 = (it >> 2) * 128;

        __syncthreads();   // previous stage's readers done
        // commit staged regs to LDS
        #pragma unroll
        for (int u = 0; u < 16; ++u) zs[sl][cg * 16 + u] = zr[u];
        #pragma unroll
        for (int v = 0; v < 8; ++v) *(float4*)&es[ex + v * 16][ec] = er[v];
        __syncthreads();

        // issue next stage's global loads (hide latency under FMA below)
        if (it + 1 < 32) {
            const int c1 = ((it + 1) & 3) * 64;
            const int k1 = ((it + 1) >> 2) * 128;
            const float* zp = z + (size_t)(b * DM + c1 + cg * 16) * SPAT + s0 + sl;
            #pragma unroll
            for (int u = 0; u < 16; ++u) zr[u] = zp[(size_t)u * SPAT];
            #pragma unroll
            for (int v = 0; v < 8; ++v)
                er[v] = *(const float4*)&embed[(size_t)(k1 + ex + v * 16) * DM + c1 + ec];
        }

        // k0==0 pass: write the transposed z tile out (fused transpose)
        if (it < 4) {
            #pragma unroll
            for (int u = 0; u < 4; ++u) {
                int row = (tid >> 4) + u * 16;
                float4 v4 = *(const float4*)&zs[row][(tid & 15) * 4];
                *(float4*)&zt[(size_t)(n0 + row) * DM + c0 + (tid & 15) * 4] = v4;
            }
        }

        if ((it & 3) == 0) {
            #pragma unroll
            for (int i = 0; i < 4; ++i)
                #pragma unroll
                for (int j = 0; j < 8; ++j) acc[i][j] = 0.f;
        }

        // inner: 64 c in steps of 4
        #pragma unroll 4
        for (int c = 0; c < 64; c += 4) {
            float4 za[4], eb[8];
            #pragma unroll
            for (int i = 0; i < 4; ++i) za[i] = *(const float4*)&zs[ti + i * 16][c];
            #pragma unroll
            for (int j = 0; j < 8; ++j) eb[j] = *(const float4*)&es[tj + j * 16][c];
            #pragma unroll
            for (int i = 0; i < 4; ++i)
                #pragma unroll
                for (int j = 0; j < 8; ++j) {
                    acc[i][j] = fmaf(za[i].x, eb[j].x, acc[i][j]);
                    acc[i][j] = fmaf(za[i].y, eb[j].y, acc[i][j]);
                    acc[i][j] = fmaf(za[i].z, eb[j].z, acc[i][j]);
                    acc[i][j] = fmaf(za[i].w, eb[j].w, acc[i][j]);
                }
        }

        // end of k-tile: fold into running argmin
        if ((it & 3) == 3) {
            #pragma unroll
            for (int j = 0; j < 8; ++j) {
                int q = k0 + tj + j * 16;
                float en = enorm[q];
                #pragma unroll
                for (int i = 0; i < 4; ++i) {
                    float v = fmaf(-2.0f, acc[i][j], en);
                    if (v < best[i]) { best[i] = v; bestk[i] = q; }
                }
            }
        }
    }

    // reduce over the 16 tj lanes (same wave), tie -> smaller k
    #pragma unroll
    for (int i = 0; i < 4; ++i) {
        float bd = best[i];
        int   bk = bestk[i];
        #pragma unroll
        for (int m = 1; m < 16; m <<= 1) {
            float od = __shfl_xor(bd, m);
            int   ok = __shfl_xor(bk, m);
            if (od < bd || (od == bd && ok < bk)) { bd = od; bk = ok; }
        }
        if (tj == 0) {
            int n = n0 + ti + i * 16;
            idx_out[n] = bk;
            dout[ZQ_SIZE + 1 + n] = (float)bk;
        }
    }
}

// per-256-row-chunk histogram (LDS atomics only). 256 blocks x 256 thr.
__global__ __launch_bounds__(256) void hist_kernel(const int* __restrict__ idx,
                                                   int* __restrict__ hist) {
    __shared__ int lh[KCODES];
    int ch = blockIdx.x, t = threadIdx.x;
    #pragma unroll
    for (int u = 0; u < 4; ++u) lh[t + u * 256] = 0;
    __syncthreads();
    int k = idx[ch * 256 + t];
    atomicAdd(&lh[k], 1);
    __syncthreads();
    #pragma unroll
    for (int u = 0; u < 4; ++u)
        hist[ch * KCODES + t + u * 256] = lh[t + u * 256];
}

// single block, 1024 threads: per-code prefix over chunks, exclusive scan -> start[],
// fused EMA cluster-size math -> csize[].
__global__ __launch_bounds__(1024) void scan_kernel(
    int* __restrict__ hist, const float* __restrict__ ema_cs,
    int* __restrict__ start, float* __restrict__ csize) {
    int k = threadIdx.x;
    int run = 0;
    for (int ch = 0; ch < 256; ++ch) {
        int t = hist[ch * KCODES + k];
        hist[ch * KCODES + k] = run;
        run += t;
    }
    int lane = k & 63, wv = k >> 6;
    int v = run;
    #pragma unroll
    for (int d = 1; d < 64; d <<= 1) {
        int t = __shfl_up(v, d);
        if (lane >= d) v += t;
    }
    __shared__ int wsum[16];
    if (lane == 63) wsum[wv] = v;
    __syncthreads();
    __shared__ int wpre[16];
    if (k == 0) {
        int s = 0;
        #pragma unroll
        for (int i = 0; i < 16; ++i) { wpre[i] = s; s += wsum[i]; }
    }
    __syncthreads();
    int excl = wpre[wv] + v - run;
    start[k] = excl;
    if (k == 1023) start[1024] = excl + run;
    float ncs = 0.99f * ema_cs[k] + 0.01f * (float)run;
    float r = ncs;
    #pragma unroll
    for (int m = 32; m > 0; m >>= 1) r += __shfl_xor(r, m);
    __shared__ float fs[16];
    if (lane == 0) fs[wv] = r;
    __syncthreads();
    __shared__ float nt;
    if (k == 0) {
        float s = 0.f;
        #pragma unroll
        for (int i = 0; i < 16; ++i) s += fs[i];
        nt = s;
    }
    __syncthreads();
    float n = nt;
    csize[k] = (ncs + 1e-5f) / (n + 1024.0f * 1e-5f) * n;
}

// stable rank within chunk + scatter row id. 256 blocks x 256 thr.
__global__ __launch_bounds__(256) void rank_scatter_kernel(
    const int* __restrict__ idx, const int* __restrict__ hist,
    const int* __restrict__ start, int* __restrict__ sorted) {
    __shared__ int lidx[256];
    int ch = blockIdx.x, t = threadIdx.x;
    int k = idx[ch * 256 + t];
    lidx[t] = k;
    __syncthreads();
    int rank = 0;
    for (int j = 0; j < 255; ++j)
        if (j < t && lidx[j] == k) ++rank;
    sorted[start[k] + hist[ch * KCODES + k] + rank] = ch * 256 + t;
}

// one block per code: coalesced row gather-sum from zt, fused newembed.
__global__ __launch_bounds__(256) void gather_kernel(
    const float* __restrict__ zt, const int* __restrict__ sorted,
    const int* __restrict__ start, const float* __restrict__ ema_es,
    const float* __restrict__ csize, float* __restrict__ newe) {
    int k = blockIdx.x, c = threadIdx.x;
    int s0 = start[k], s1 = start[k + 1];
    float acc = 0.f;
    for (int i = s0; i < s1; ++i) {
        int n = sorted[i];
        acc += zt[(size_t)n * DM + c];
    }
    size_t o = (size_t)k * DM + c;
    newe[o] = (0.99f * ema_es[o] + 0.01f * acc) / csize[k];
}

// z_q gather into (B,C,D,H,W) layout + per-block loss partial.
// 8192 blocks x 256 threads x 8 elements = 16777216. Overwrites zt region.
__global__ __launch_bounds__(256) void output_kernel(
    const float* __restrict__ z, const float* __restrict__ newe,
    const int* __restrict__ idx, float* __restrict__ dout,
    float* __restrict__ lossp) {
    int gid = blockIdx.x * 256 + threadIdx.x;
    float lsum = 0.f;
    #pragma unroll
    for (int it = 0; it < 8; ++it) {
        int o = gid + it * (8192 * 256);
        int s = o & 16383, t2 = o >> 14;
        int c = t2 & 255, b = t2 >> 8;
        int n = (b << 14) + s;
        int k = idx[n];
        float v = newe[(size_t)k * DM + c];
        float zv = z[o];
        dout[o] = v;
        float d = zv - v;
        lsum = fmaf(d, d, lsum);
    }
    #pragma unroll
    for (int m = 32; m > 0; m >>= 1) lsum += __shfl_xor(lsum, m);
    __shared__ float sm[4];
    int t = threadIdx.x;
    if ((t & 63) == 0) sm[t >> 6] = lsum;
    __syncthreads();
    if (t == 0) lossp[blockIdx.x] = sm[0] + sm[1] + sm[2] + sm[3];
}

__global__ __launch_bounds__(256) void loss_final_kernel(const float* __restrict__ lossp,
                                                         float* __restrict__ dout) {
    int t = threadIdx.x;
    float v = 0.f;
    for (int i = t; i < 8192; i += 256) v += lossp[i];
    #pragma unroll
    for (int m = 32; m > 0; m >>= 1) v += __shfl_xor(v, m);
    __shared__ float sm[4];
    if ((t & 63) == 0) sm[t >> 6] = v;
    __syncthreads();
    if (t == 0) dout[ZQ_SIZE] = 0.25f * ((sm[0] + sm[1] + sm[2] + sm[3]) / 16777216.0f);
}

extern "C" void kernel_launch(void* const* d_in, const int* in_sizes, int n_in,
                              void* d_out, int out_size, void* d_ws, size_t ws_size,
                              hipStream_t stream) {
    const float* z      = (const float*)d_in[0];
    const float* embed  = (const float*)d_in[1];
    const float* ema_cs = (const float*)d_in[2];
    const float* ema_es = (const float*)d_in[3];
    float* out = (float*)d_out;
    float* ws  = (float*)d_ws;

    float* enorm = ws + WS_ENORM;
    float* csize = ws + WS_CSIZE;
    int*   start = (int*)(ws + WS_START);
    float* lossp = ws + WS_LOSSP;
    int*   hist  = (int*)(ws + WS_HIST);
    int*   sortd = (int*)(ws + WS_SORT);
    int*   idx   = (int*)(ws + WS_IDX);
    float* newe  = ws + WS_NEWE;
    float* zt    = out;   // d_out[0..ZQ_SIZE) as scratch until output_kernel

    enorm_kernel<<<KCODES, 256, 0, stream>>>(embed, enorm);
    argmin_kernel<<<NTOT / 64, 256, 0, stream>>>(z, embed, enorm, idx, out, zt);
    hist_kernel<<<256, 256, 0, stream>>>(idx, hist);
    scan_kernel<<<1, 1024, 0, stream>>>(hist, ema_cs, start, csize);
    rank_scatter_kernel<<<256, 256, 0, stream>>>(idx, hist, start, sortd);
    gather_kernel<<<KCODES, 256, 0, stream>>>(zt, sortd, start, ema_es, csize, newe);
    output_kernel<<<8192, 256, 0, stream>>>(z, newe, idx, out, lossp);
    loss_final_kernel<<<1, 256, 0, stream>>>(lossp, out);
}